// Round 7
// baseline (1023.921 us; speedup 1.0000x reference)
//
#include <hip/hip_runtime.h>

// AttackLSTM R7. B=256, T=512. a0:(1->64) a1,a2:(64->64) b0:(64->1) b1,b2:(1->1)
// R6 post-mortem: rec_k 202us, VALUBusy 44% -> ~50% stall (serial per-step
// chain: reduce/act/gather/update/ds roundtrip/barrier ~ 250cy) + ~420cy issue.
// R7 halves dot issue with v_pk_fma_f32 (2 fp32 MACs/inst): each thread reads
// the FULL h as wave-uniform ds_read_b64 pairs (HW broadcast, conflict-free)
// and runs 32 pk_fma on register weight pairs. Quad-DPP now only gathers the
// 4 gate activations. proj/preb0/b_rec unchanged.

#define BB 256
#define TT 512
#define WIN 128

typedef float v2f __attribute__((ext_vector_type(2)));

__device__ __forceinline__ float sig_(float x) {
  return __builtin_amdgcn_rcpf(1.f + __builtin_amdgcn_exp2f(-1.44269504f * x));
}
__device__ __forceinline__ float tanh_(float x) {
  return __builtin_fmaf(2.f, __builtin_amdgcn_rcpf(1.f + __builtin_amdgcn_exp2f(-2.88539008f * x)), -1.f);
}

// DPP quad_perm broadcast of quad-lane K to all 4 lanes of each quad.
template <int K>
__device__ __forceinline__ float qb_(float v) {
  return __int_as_float(__builtin_amdgcn_update_dpp(
      0, __float_as_int(v), (K | (K << 2) | (K << 4) | (K << 6)), 0xF, 0xF, true));
}

// Barrier that only waits on LDS ops: global loads/stores stay in flight.
__device__ __forceinline__ void ldsbar_() {
  asm volatile("s_waitcnt lgkmcnt(0)\n\ts_barrier" ::: "memory");
}

// acc(pair) += w(pair) * h(pair)   -- one VOP3P packed-fp32 FMA
#define PKFMA(a, w, h) \
  asm("v_pk_fma_f32 %0, %1, %2, %0" : "+v"(a) : "v"(w), "v"(h))

#define KEEPP(a) asm volatile("" : "+v"(a))

// MODE 0: input = x [B,T,1] via w_ih0; MODE 1: input = pre [B,T,256] identity
// layout; thread g reads element (g&3)*64 + (g>>2) of its row.
template <int MODE, typename PreT>
__global__ __launch_bounds__(256, 1) void rec_k(
    const float* __restrict__ x,
    const PreT* __restrict__ pre_in,
    const float* __restrict__ w_ih0,
    const float* __restrict__ w_hh,   // [256,64]
    const float* __restrict__ b_ih,
    const float* __restrict__ b_hh,
    float* __restrict__ h_out)        // [B,T,64]
{
  const int b = blockIdx.x;
  const int g = threadIdx.x;
  const int q = g & 3;     // gate 0=i 1=f 2=g 3=o
  const int hid = g >> 2;  // hidden unit
  const int row = q * 64 + hid;
  const int ofs = q * 64 + hid;

  __shared__ float hist[(WIN + 1) * 64];  // hist[u][hid]
  __shared__ float xs[TT];                // MODE0 input row

  // weight row as 32 register pairs (for pk_fma)
  v2f wh[32];
  {
    const v2f* p = reinterpret_cast<const v2f*>(w_hh + row * 64);
#pragma unroll
    for (int i = 0; i < 32; ++i) wh[i] = p[i];
  }
#pragma unroll
  for (int i = 0; i < 32; ++i) KEEPP(wh[i]);

  const float bias = b_ih[row] + b_hh[row];
  float wi0 = 0.f;
  if constexpr (MODE == 0) wi0 = w_ih0[row];

  if constexpr (MODE == 0) {
    xs[g] = x[(size_t)b * TT + g];
    xs[g + 256] = x[(size_t)b * TT + 256 + g];
  }
  if (g < 64) hist[g] = 0.f;

  float cur[8], nxt[8];
  if constexpr (MODE == 1) {
#pragma unroll
    for (int u = 0; u < 8; ++u) cur[u] = (float)pre_in[((size_t)b * TT + u) * 256 + ofs];
#pragma unroll
    for (int u = 0; u < 8; ++u) nxt[u] = (float)pre_in[((size_t)b * TT + 8 + u) * 256 + ofs];
  }
  __syncthreads();

  float c = 0.f;

  for (int tb = 0; tb < TT; tb += 8) {
    const int lb = tb & (WIN - 1);
#pragma unroll
    for (int u = 0; u < 8; ++u) {
      const int lu = lb + u;

      float base;
      if constexpr (MODE == 0) base = __builtin_fmaf(wi0, xs[tb + u], bias);
      else base = bias + cur[u];

      // full h as wave-uniform b64 pairs (HW broadcast), 32 pk_fma
      const v2f* hp = reinterpret_cast<const v2f*>(hist + lu * 64);
      v2f acc0 = {0.f, 0.f}, acc1 = {0.f, 0.f}, acc2 = {0.f, 0.f}, acc3 = {0.f, 0.f};
#pragma unroll
      for (int k = 0; k < 8; ++k) {
        v2f h0 = hp[4 * k], h1 = hp[4 * k + 1], h2 = hp[4 * k + 2], h3 = hp[4 * k + 3];
        PKFMA(acc0, wh[4 * k], h0);
        PKFMA(acc1, wh[4 * k + 1], h1);
        PKFMA(acc2, wh[4 * k + 2], h2);
        PKFMA(acc3, wh[4 * k + 3], h3);
      }
      float s0 = acc0.x + acc0.y, s1 = acc1.x + acc1.y;
      float s2 = acc2.x + acc2.y, s3 = acc3.x + acc3.y;
      float pre = base + ((s0 + s1) + (s2 + s3));

      float sc = (q == 2) ? -2.88539008f : -1.44269504f;
      float e = __builtin_amdgcn_exp2f(sc * pre);
      float r = __builtin_amdgcn_rcpf(1.f + e);
      float act = (q == 2) ? __builtin_fmaf(2.f, r, -1.f) : r;

      float gi = qb_<0>(act);
      float gf = qb_<1>(act);
      float gg = qb_<2>(act);
      float go = qb_<3>(act);

      c = __builtin_fmaf(gf, c, gi * gg);
      float h = go * tanh_(c);
      if (q == 0) hist[(lu + 1) * 64 + hid] = h;
      ldsbar_();
    }

    if constexpr (MODE == 1) {
#pragma unroll
      for (int u = 0; u < 8; ++u) cur[u] = nxt[u];
      if (tb + 16 < TT) {
#pragma unroll
        for (int u = 0; u < 8; ++u)
          nxt[u] = (float)pre_in[((size_t)b * TT + tb + 16 + u) * 256 + ofs];
      }
    }

    if (((tb + 8) & (WIN - 1)) == 0) {
      const int t0 = tb + 8 - WIN;
      float4* dst = reinterpret_cast<float4*>(h_out + ((size_t)b * TT + t0) * 64);
      const float4* src = reinterpret_cast<const float4*>(hist + 64);
#pragma unroll
      for (int i = 0; i < 8; ++i) dst[g + 256 * i] = src[g + 256 * i];
      if (g < 64) hist[g] = hist[WIN * 64 + g];
      ldsbar_();
    }
  }
}

// pre[rowm, c] = w[c,:]·h[rowm,:] (identity layout, coalesced stores).
template <typename PreT>
__global__ __launch_bounds__(256) void proj_k(
    const float* __restrict__ h,   // [M,64]
    const float* __restrict__ w,   // [256,64]
    PreT* __restrict__ pre)        // [M,256]
{
  __shared__ float hs[64 * 65];    // hs[k][r]
  __shared__ float ws[64 * 132];   // ws[k][c]
  const int tid = threadIdx.x;
  const int bm = blockIdx.x >> 1, half = blockIdx.x & 1;
  const size_t row0 = (size_t)bm * 64;
  const int c0 = half * 128;

#pragma unroll
  for (int i = 0; i < 16; ++i) {
    int idx = tid + 256 * i;
    int r = idx >> 6, k = idx & 63;
    hs[k * 65 + r] = h[(row0 + r) * 64 + k];
  }
#pragma unroll
  for (int i = 0; i < 32; ++i) {
    int idx = tid + 256 * i;
    int cc = idx >> 6, k = idx & 63;
    ws[k * 132 + cc] = w[(size_t)(c0 + cc) * 64 + k];
  }
  __syncthreads();

  const int rg = tid >> 4;
  const int cg = tid & 15;
  float acc[4][8];
#pragma unroll
  for (int r = 0; r < 4; ++r)
#pragma unroll
    for (int cc = 0; cc < 8; ++cc) acc[r][cc] = 0.f;

#pragma unroll 4
  for (int k = 0; k < 64; ++k) {
    float4 hv = *reinterpret_cast<const float4*>(&hs[k * 65 + 4 * rg]);
    float4 wa = *reinterpret_cast<const float4*>(&ws[k * 132 + 8 * cg]);
    float4 wb = *reinterpret_cast<const float4*>(&ws[k * 132 + 8 * cg + 4]);
    float hr[4] = {hv.x, hv.y, hv.z, hv.w};
    float wc[8] = {wa.x, wa.y, wa.z, wa.w, wb.x, wb.y, wb.z, wb.w};
#pragma unroll
    for (int r = 0; r < 4; ++r)
#pragma unroll
      for (int cc = 0; cc < 8; ++cc)
        acc[r][cc] = __builtin_fmaf(hr[r], wc[cc], acc[r][cc]);
  }

#pragma unroll
  for (int r = 0; r < 4; ++r) {
    size_t rowm = row0 + 4 * rg + r;
    PreT* dst = pre + rowm * 256 + c0 + 8 * cg;
#pragma unroll
    for (int cc = 0; cc < 8; ++cc) dst[cc] = (PreT)acc[r][cc];
  }
}

// pre_b0[t,b,q] = b_ih[q]+b_hh[q] + w[q,:]·h[b,t,:]
__global__ __launch_bounds__(256) void preb0_k(
    const float* __restrict__ h, const float* __restrict__ w,
    const float* __restrict__ bi, const float* __restrict__ bh,
    float* __restrict__ pre) {
  __shared__ float hs[64 * 68];
  const int tid = threadIdx.x;
  const int r = tid >> 2, q = tid & 3;

  float wr[64];
  {
    const float4* p = reinterpret_cast<const float4*>(w + q * 64);
#pragma unroll
    for (int i = 0; i < 16; ++i) {
      float4 v = p[i];
      wr[4 * i] = v.x; wr[4 * i + 1] = v.y; wr[4 * i + 2] = v.z; wr[4 * i + 3] = v.w;
    }
  }
  const float bias = bi[q] + bh[q];

  const size_t base = (size_t)blockIdx.x * 64;
  {
    const float4* src = reinterpret_cast<const float4*>(h + base * 64);
#pragma unroll
    for (int i = 0; i < 4; ++i) {
      int f = tid + 256 * i;
      int rr = f >> 4, kk = f & 15;
      *reinterpret_cast<float4*>(hs + rr * 68 + kk * 4) = src[f];
    }
  }
  __syncthreads();

  const float4* hr = reinterpret_cast<const float4*>(hs + r * 68);
  float a0 = bias, a1 = 0.f, a2 = 0.f, a3 = 0.f;
#pragma unroll
  for (int i = 0; i < 16; ++i) {
    float4 hv = hr[i];
    a0 = __builtin_fmaf(wr[4 * i], hv.x, a0);
    a1 = __builtin_fmaf(wr[4 * i + 1], hv.y, a1);
    a2 = __builtin_fmaf(wr[4 * i + 2], hv.z, a2);
    a3 = __builtin_fmaf(wr[4 * i + 3], hv.w, a3);
  }
  const size_t rowg = base + r;
  const int b = (int)(rowg / TT), t = (int)(rowg % TT);
  pre[((size_t)t * BB + b) * 4 + q] = (a0 + a1) + (a2 + a3);
}

// Fused b0->b1->b2, chunk-8 register pipeline (static indices).
__global__ __launch_bounds__(64, 1) void b_rec_k(
    const float* __restrict__ pre,  // [T,B,4]
    const float* __restrict__ w_hh_b0,
    const float* __restrict__ w_ih_b1, const float* __restrict__ w_hh_b1,
    const float* __restrict__ b_ih_b1, const float* __restrict__ b_hh_b1,
    const float* __restrict__ w_ih_b2, const float* __restrict__ w_hh_b2,
    const float* __restrict__ b_ih_b2, const float* __restrict__ b_hh_b2,
    float* __restrict__ out) {
  const int b = blockIdx.x * 64 + threadIdx.x;
  float wh0[4], wi1[4], wh1[4], bb1[4], wi2[4], wh2[4], bb2[4];
#pragma unroll
  for (int k = 0; k < 4; ++k) {
    wh0[k] = w_hh_b0[k];
    wi1[k] = w_ih_b1[k]; wh1[k] = w_hh_b1[k]; bb1[k] = b_ih_b1[k] + b_hh_b1[k];
    wi2[k] = w_ih_b2[k]; wh2[k] = w_hh_b2[k]; bb2[k] = b_ih_b2[k] + b_hh_b2[k];
  }
  float h0 = 0.f, c0 = 0.f, h1 = 0.f, c1 = 0.f, h2 = 0.f, c2 = 0.f;

  const float4* pp = reinterpret_cast<const float4*>(pre);
  float4 cur[8], nxt[8];
#pragma unroll
  for (int u = 0; u < 8; ++u) cur[u] = pp[u * BB + b];
#pragma unroll
  for (int u = 0; u < 8; ++u) nxt[u] = pp[(8 + u) * BB + b];

  for (int tb = 0; tb < TT; tb += 8) {
    float ob[8];
#pragma unroll
    for (int u = 0; u < 8; ++u) {
      float4 p = cur[u];
      float i0 = sig_(__builtin_fmaf(wh0[0], h0, p.x));
      float f0 = sig_(__builtin_fmaf(wh0[1], h0, p.y));
      float g0 = tanh_(__builtin_fmaf(wh0[2], h0, p.z));
      float o0 = sig_(__builtin_fmaf(wh0[3], h0, p.w));
      c0 = __builtin_fmaf(f0, c0, i0 * g0);
      h0 = o0 * tanh_(c0);

      float i1 = sig_(bb1[0] + __builtin_fmaf(wi1[0], h0, wh1[0] * h1));
      float f1 = sig_(bb1[1] + __builtin_fmaf(wi1[1], h0, wh1[1] * h1));
      float g1 = tanh_(bb1[2] + __builtin_fmaf(wi1[2], h0, wh1[2] * h1));
      float o1 = sig_(bb1[3] + __builtin_fmaf(wi1[3], h0, wh1[3] * h1));
      c1 = __builtin_fmaf(f1, c1, i1 * g1);
      h1 = o1 * tanh_(c1);

      float i2 = sig_(bb2[0] + __builtin_fmaf(wi2[0], h1, wh2[0] * h2));
      float f2 = sig_(bb2[1] + __builtin_fmaf(wi2[1], h1, wh2[1] * h2));
      float g2 = tanh_(bb2[2] + __builtin_fmaf(wi2[2], h1, wh2[2] * h2));
      float o2 = sig_(bb2[3] + __builtin_fmaf(wi2[3], h1, wh2[3] * h2));
      c2 = __builtin_fmaf(f2, c2, i2 * g2);
      h2 = o2 * tanh_(c2);
      ob[u] = h2;
    }
    float4 s0 = {ob[0], ob[1], ob[2], ob[3]};
    float4 s1 = {ob[4], ob[5], ob[6], ob[7]};
    float4* op = reinterpret_cast<float4*>(out + (size_t)b * TT + tb);
    op[0] = s0;
    op[1] = s1;
#pragma unroll
    for (int u = 0; u < 8; ++u) cur[u] = nxt[u];
    if (tb + 16 < TT) {
#pragma unroll
      for (int u = 0; u < 8; ++u) nxt[u] = pp[(tb + 16 + u) * BB + b];
    }
  }
}

template <typename PreT>
static void launch_all(void* const* d_in, void* d_out, void* d_ws, hipStream_t stream) {
  const float* x      = (const float*)d_in[0];
  const float* wih_a0 = (const float*)d_in[1];
  const float* whh_a0 = (const float*)d_in[2];
  const float* bih_a0 = (const float*)d_in[3];
  const float* bhh_a0 = (const float*)d_in[4];
  const float* wih_a1 = (const float*)d_in[5];
  const float* whh_a1 = (const float*)d_in[6];
  const float* bih_a1 = (const float*)d_in[7];
  const float* bhh_a1 = (const float*)d_in[8];
  const float* wih_a2 = (const float*)d_in[9];
  const float* whh_a2 = (const float*)d_in[10];
  const float* bih_a2 = (const float*)d_in[11];
  const float* bhh_a2 = (const float*)d_in[12];
  const float* wih_b0 = (const float*)d_in[13];
  const float* whh_b0 = (const float*)d_in[14];
  const float* bih_b0 = (const float*)d_in[15];
  const float* bhh_b0 = (const float*)d_in[16];
  const float* wih_b1 = (const float*)d_in[17];
  const float* whh_b1 = (const float*)d_in[18];
  const float* bih_b1 = (const float*)d_in[19];
  const float* bhh_b1 = (const float*)d_in[20];
  const float* wih_b2 = (const float*)d_in[21];
  const float* whh_b2 = (const float*)d_in[22];
  const float* bih_b2 = (const float*)d_in[23];
  const float* bhh_b2 = (const float*)d_in[24];

  const size_t M = (size_t)BB * TT;
  PreT* P   = (PreT*)d_ws;                                     // [M,256]
  float* hA = (float*)((char*)d_ws + M * 256 * sizeof(PreT));  // [M,64]
  float* pb0 = hA + M * 64;                                    // [T,B,4]
  float* out = (float*)d_out;

  rec_k<0, PreT><<<BB, 256, 0, stream>>>(x, nullptr, wih_a0, whh_a0, bih_a0, bhh_a0, hA);
  proj_k<PreT><<<(int)(M / 64) * 2, 256, 0, stream>>>(hA, wih_a1, P);
  rec_k<1, PreT><<<BB, 256, 0, stream>>>(nullptr, P, nullptr, whh_a1, bih_a1, bhh_a1, hA);
  proj_k<PreT><<<(int)(M / 64) * 2, 256, 0, stream>>>(hA, wih_a2, P);
  rec_k<1, PreT><<<BB, 256, 0, stream>>>(nullptr, P, nullptr, whh_a2, bih_a2, bhh_a2, hA);
  preb0_k<<<(int)(M / 64), 256, 0, stream>>>(hA, wih_b0, bih_b0, bhh_b0, pb0);
  b_rec_k<<<4, 64, 0, stream>>>(pb0, whh_b0, wih_b1, whh_b1, bih_b1, bhh_b1,
                                wih_b2, whh_b2, bih_b2, bhh_b2, out);
}

extern "C" void kernel_launch(void* const* d_in, const int* in_sizes, int n_in,
                              void* d_out, int out_size, void* d_ws, size_t ws_size,
                              hipStream_t stream) {
  const size_t M = (size_t)BB * TT;
  const size_t need_f32 = M * 256 * 4 + M * 64 * 4 + (size_t)TT * BB * 4 * 4;
  if (ws_size >= need_f32) launch_all<float>(d_in, d_out, d_ws, stream);
  else launch_all<_Float16>(d_in, d_out, d_ws, stream);
}

// Round 8
// 919.366 us; speedup vs baseline: 1.1137x; 1.1137x over previous
//
#include <hip/hip_runtime.h>

// AttackLSTM R8. B=256, T=512. a0:(1->64) a1,a2:(64->64) b0:(64->1) b1,b2:(1->1)
// R7 post-mortem: full-h wave-uniform ds_read_b64 (32/thread/step) was
// LDS-issue-bound -> regression. Reverted to R6 quad-chunk + fmac_dpp dot.
// R6 anomaly: VGPR_Count=64 < ~110 live -> compiler targeted 8-wave occupancy
// and cycled weights through AGPRs (v_accvgpr_read per use in-loop). R8 adds
// amdgpu_waves_per_eu(1,1) (we really run 1 wave/SIMD) -> ~512-reg budget.
// Also: inter-layer pre buffer forced to fp16 (err ~5e-4 << 5e-3 threshold),
// halving proj stores + rec fetches.

#define BB 256
#define TT 512
#define WIN 128

__device__ __forceinline__ float sig_(float x) {
  return __builtin_amdgcn_rcpf(1.f + __builtin_amdgcn_exp2f(-1.44269504f * x));
}
__device__ __forceinline__ float tanh_(float x) {
  return __builtin_fmaf(2.f, __builtin_amdgcn_rcpf(1.f + __builtin_amdgcn_exp2f(-2.88539008f * x)), -1.f);
}

// DPP quad_perm broadcast of quad-lane K to all 4 lanes of each quad.
template <int K>
__device__ __forceinline__ float qb_(float v) {
  return __int_as_float(__builtin_amdgcn_update_dpp(
      0, __float_as_int(v), (K | (K << 2) | (K << 4) | (K << 6)), 0xF, 0xF, true));
}

// Barrier that only waits on LDS ops: global loads/stores stay in flight.
__device__ __forceinline__ void ldsbar_() {
  asm volatile("s_waitcnt lgkmcnt(0)\n\ts_barrier" ::: "memory");
}

#define KEEP4(a, i) asm volatile("" : "+v"(a[(i)]), "+v"(a[(i)+1]), "+v"(a[(i)+2]), "+v"(a[(i)+3]))
#define KEEP16(a, i) do { KEEP4(a, (i)); KEEP4(a, (i)+4); KEEP4(a, (i)+8); KEEP4(a, (i)+12); } while (0)
#define KEEP64(a) do { KEEP16(a, 0); KEEP16(a, 16); KEEP16(a, 32); KEEP16(a, 48); } while (0)

// Fused broadcast+FMA: acc += quad_broadcast<P>(h) * w  (one VOP2-DPP inst).
#define QPSTR(P) "quad_perm:[" #P "," #P "," #P "," #P "]"
#define FMACD(a, h, w, P)                                             \
  asm("v_fmac_f32_dpp %0, %1, %2 " QPSTR(P) " row_mask:0xf bank_mask:0xf" \
      : "+v"(a) : "v"(h), "v"(w))
#define FM(P, M) FMACD(acc[(M) & 7], hx[M], wh[16 * (P) + (M)], P)
#define PHASE(P)                                                     \
  do {                                                               \
    FM(P, 0); FM(P, 1); FM(P, 2); FM(P, 3);                          \
    FM(P, 4); FM(P, 5); FM(P, 6); FM(P, 7);                          \
    FM(P, 8); FM(P, 9); FM(P, 10); FM(P, 11);                        \
    FM(P, 12); FM(P, 13); FM(P, 14); FM(P, 15);                      \
  } while (0)

// MODE 0: input = x [B,T,1] via w_ih0; MODE 1: input = pre [B,T,256] identity
// layout; thread g reads element (g&3)*64 + (g>>2) of its row.
template <int MODE, typename PreT>
__global__ __attribute__((amdgpu_flat_work_group_size(256, 256),
                          amdgpu_waves_per_eu(1, 1)))
void rec_k(
    const float* __restrict__ x,
    const PreT* __restrict__ pre_in,
    const float* __restrict__ w_ih0,
    const float* __restrict__ w_hh,   // [256,64]
    const float* __restrict__ b_ih,
    const float* __restrict__ b_hh,
    float* __restrict__ h_out)        // [B,T,64]
{
  const int b = blockIdx.x;
  const int g = threadIdx.x;
  const int q = g & 3;     // gate 0=i 1=f 2=g 3=o
  const int hid = g >> 2;  // hidden unit
  const int row = q * 64 + hid;
  const int ofs = q * 64 + hid;

  __shared__ float hist[(WIN + 1) * 64];  // hist[u][hid]
  __shared__ float xs[TT];                // MODE0 input row

  float wh[64];
  {
    const float4* p = reinterpret_cast<const float4*>(w_hh + row * 64);
#pragma unroll
    for (int i = 0; i < 16; ++i) {
      float4 v = p[i];
      wh[4 * i] = v.x; wh[4 * i + 1] = v.y; wh[4 * i + 2] = v.z; wh[4 * i + 3] = v.w;
    }
  }
  KEEP64(wh);

  const float bias = b_ih[row] + b_hh[row];
  float wi0 = 0.f;
  if constexpr (MODE == 0) wi0 = w_ih0[row];

  if constexpr (MODE == 0) {
    xs[g] = x[(size_t)b * TT + g];
    xs[g + 256] = x[(size_t)b * TT + 256 + g];
  }
  if (g < 64) hist[g] = 0.f;

  float cur[8], nxt[8];
  if constexpr (MODE == 1) {
#pragma unroll
    for (int u = 0; u < 8; ++u) cur[u] = (float)pre_in[((size_t)b * TT + u) * 256 + ofs];
#pragma unroll
    for (int u = 0; u < 8; ++u) nxt[u] = (float)pre_in[((size_t)b * TT + 8 + u) * 256 + ofs];
  }
  __syncthreads();

  float c = 0.f;

  for (int tb = 0; tb < TT; tb += 8) {
    const int lb = tb & (WIN - 1);
#pragma unroll
    for (int u = 0; u < 8; ++u) {
      const int lu = lb + u;
      // own h chunk: hist[lu][16q .. 16q+15]
      float hx[16];
      {
        const float4* hp = reinterpret_cast<const float4*>(hist + lu * 64 + 16 * q);
        float4 h0 = hp[0], h1 = hp[1], h2 = hp[2], h3 = hp[3];
        hx[0] = h0.x; hx[1] = h0.y; hx[2] = h0.z; hx[3] = h0.w;
        hx[4] = h1.x; hx[5] = h1.y; hx[6] = h1.z; hx[7] = h1.w;
        hx[8] = h2.x; hx[9] = h2.y; hx[10] = h2.z; hx[11] = h2.w;
        hx[12] = h3.x; hx[13] = h3.y; hx[14] = h3.z; hx[15] = h3.w;
      }
      float acc[8];
      if constexpr (MODE == 0) acc[0] = __builtin_fmaf(wi0, xs[tb + u], bias);
      else acc[0] = bias + cur[u];
#pragma unroll
      for (int m = 1; m < 8; ++m) acc[m] = 0.f;

      PHASE(0); PHASE(1); PHASE(2); PHASE(3);

      float s0 = acc[0] + acc[1], s1 = acc[2] + acc[3];
      float s2 = acc[4] + acc[5], s3 = acc[6] + acc[7];
      float pre = (s0 + s1) + (s2 + s3);

      float sc = (q == 2) ? -2.88539008f : -1.44269504f;
      float e = __builtin_amdgcn_exp2f(sc * pre);
      float r = __builtin_amdgcn_rcpf(1.f + e);
      float act = (q == 2) ? __builtin_fmaf(2.f, r, -1.f) : r;

      float gi = qb_<0>(act);
      float gf = qb_<1>(act);
      float gg = qb_<2>(act);
      float go = qb_<3>(act);

      c = __builtin_fmaf(gf, c, gi * gg);
      float h = go * tanh_(c);
      if (q == 0) hist[(lu + 1) * 64 + hid] = h;
      ldsbar_();
    }

    if constexpr (MODE == 1) {
#pragma unroll
      for (int u = 0; u < 8; ++u) cur[u] = nxt[u];
      if (tb + 16 < TT) {
#pragma unroll
        for (int u = 0; u < 8; ++u)
          nxt[u] = (float)pre_in[((size_t)b * TT + tb + 16 + u) * 256 + ofs];
      }
    }

    if (((tb + 8) & (WIN - 1)) == 0) {
      const int t0 = tb + 8 - WIN;
      float4* dst = reinterpret_cast<float4*>(h_out + ((size_t)b * TT + t0) * 64);
      const float4* src = reinterpret_cast<const float4*>(hist + 64);
#pragma unroll
      for (int i = 0; i < 8; ++i) dst[g + 256 * i] = src[g + 256 * i];
      if (g < 64) hist[g] = hist[WIN * 64 + g];
      ldsbar_();
    }
  }
}

// pre[rowm, c] = w[c,:]·h[rowm,:] (identity layout, coalesced stores).
template <typename PreT>
__global__ __launch_bounds__(256) void proj_k(
    const float* __restrict__ h,   // [M,64]
    const float* __restrict__ w,   // [256,64]
    PreT* __restrict__ pre)        // [M,256]
{
  __shared__ float hs[64 * 65];    // hs[k][r]
  __shared__ float ws[64 * 132];   // ws[k][c]
  const int tid = threadIdx.x;
  const int bm = blockIdx.x >> 1, half = blockIdx.x & 1;
  const size_t row0 = (size_t)bm * 64;
  const int c0 = half * 128;

#pragma unroll
  for (int i = 0; i < 16; ++i) {
    int idx = tid + 256 * i;
    int r = idx >> 6, k = idx & 63;
    hs[k * 65 + r] = h[(row0 + r) * 64 + k];
  }
#pragma unroll
  for (int i = 0; i < 32; ++i) {
    int idx = tid + 256 * i;
    int cc = idx >> 6, k = idx & 63;
    ws[k * 132 + cc] = w[(size_t)(c0 + cc) * 64 + k];
  }
  __syncthreads();

  const int rg = tid >> 4;
  const int cg = tid & 15;
  float acc[4][8];
#pragma unroll
  for (int r = 0; r < 4; ++r)
#pragma unroll
    for (int cc = 0; cc < 8; ++cc) acc[r][cc] = 0.f;

#pragma unroll 4
  for (int k = 0; k < 64; ++k) {
    float4 hv = *reinterpret_cast<const float4*>(&hs[k * 65 + 4 * rg]);
    float4 wa = *reinterpret_cast<const float4*>(&ws[k * 132 + 8 * cg]);
    float4 wb = *reinterpret_cast<const float4*>(&ws[k * 132 + 8 * cg + 4]);
    float hr[4] = {hv.x, hv.y, hv.z, hv.w};
    float wc[8] = {wa.x, wa.y, wa.z, wa.w, wb.x, wb.y, wb.z, wb.w};
#pragma unroll
    for (int r = 0; r < 4; ++r)
#pragma unroll
      for (int cc = 0; cc < 8; ++cc)
        acc[r][cc] = __builtin_fmaf(hr[r], wc[cc], acc[r][cc]);
  }

#pragma unroll
  for (int r = 0; r < 4; ++r) {
    size_t rowm = row0 + 4 * rg + r;
    PreT* dst = pre + rowm * 256 + c0 + 8 * cg;
#pragma unroll
    for (int cc = 0; cc < 8; ++cc) dst[cc] = (PreT)acc[r][cc];
  }
}

// pre_b0[t,b,q] = b_ih[q]+b_hh[q] + w[q,:]·h[b,t,:]
__global__ __launch_bounds__(256) void preb0_k(
    const float* __restrict__ h, const float* __restrict__ w,
    const float* __restrict__ bi, const float* __restrict__ bh,
    float* __restrict__ pre) {
  __shared__ float hs[64 * 68];
  const int tid = threadIdx.x;
  const int r = tid >> 2, q = tid & 3;

  float wr[64];
  {
    const float4* p = reinterpret_cast<const float4*>(w + q * 64);
#pragma unroll
    for (int i = 0; i < 16; ++i) {
      float4 v = p[i];
      wr[4 * i] = v.x; wr[4 * i + 1] = v.y; wr[4 * i + 2] = v.z; wr[4 * i + 3] = v.w;
    }
  }
  const float bias = bi[q] + bh[q];

  const size_t base = (size_t)blockIdx.x * 64;
  {
    const float4* src = reinterpret_cast<const float4*>(h + base * 64);
#pragma unroll
    for (int i = 0; i < 4; ++i) {
      int f = tid + 256 * i;
      int rr = f >> 4, kk = f & 15;
      *reinterpret_cast<float4*>(hs + rr * 68 + kk * 4) = src[f];
    }
  }
  __syncthreads();

  const float4* hr = reinterpret_cast<const float4*>(hs + r * 68);
  float a0 = bias, a1 = 0.f, a2 = 0.f, a3 = 0.f;
#pragma unroll
  for (int i = 0; i < 16; ++i) {
    float4 hv = hr[i];
    a0 = __builtin_fmaf(wr[4 * i], hv.x, a0);
    a1 = __builtin_fmaf(wr[4 * i + 1], hv.y, a1);
    a2 = __builtin_fmaf(wr[4 * i + 2], hv.z, a2);
    a3 = __builtin_fmaf(wr[4 * i + 3], hv.w, a3);
  }
  const size_t rowg = base + r;
  const int b = (int)(rowg / TT), t = (int)(rowg % TT);
  pre[((size_t)t * BB + b) * 4 + q] = (a0 + a1) + (a2 + a3);
}

// Fused b0->b1->b2, chunk-8 register pipeline (static indices).
__global__ __launch_bounds__(64, 1) void b_rec_k(
    const float* __restrict__ pre,  // [T,B,4]
    const float* __restrict__ w_hh_b0,
    const float* __restrict__ w_ih_b1, const float* __restrict__ w_hh_b1,
    const float* __restrict__ b_ih_b1, const float* __restrict__ b_hh_b1,
    const float* __restrict__ w_ih_b2, const float* __restrict__ w_hh_b2,
    const float* __restrict__ b_ih_b2, const float* __restrict__ b_hh_b2,
    float* __restrict__ out) {
  const int b = blockIdx.x * 64 + threadIdx.x;
  float wh0[4], wi1[4], wh1[4], bb1[4], wi2[4], wh2[4], bb2[4];
#pragma unroll
  for (int k = 0; k < 4; ++k) {
    wh0[k] = w_hh_b0[k];
    wi1[k] = w_ih_b1[k]; wh1[k] = w_hh_b1[k]; bb1[k] = b_ih_b1[k] + b_hh_b1[k];
    wi2[k] = w_ih_b2[k]; wh2[k] = w_hh_b2[k]; bb2[k] = b_ih_b2[k] + b_hh_b2[k];
  }
  float h0 = 0.f, c0 = 0.f, h1 = 0.f, c1 = 0.f, h2 = 0.f, c2 = 0.f;

  const float4* pp = reinterpret_cast<const float4*>(pre);
  float4 cur[8], nxt[8];
#pragma unroll
  for (int u = 0; u < 8; ++u) cur[u] = pp[u * BB + b];
#pragma unroll
  for (int u = 0; u < 8; ++u) nxt[u] = pp[(8 + u) * BB + b];

  for (int tb = 0; tb < TT; tb += 8) {
    float ob[8];
#pragma unroll
    for (int u = 0; u < 8; ++u) {
      float4 p = cur[u];
      float i0 = sig_(__builtin_fmaf(wh0[0], h0, p.x));
      float f0 = sig_(__builtin_fmaf(wh0[1], h0, p.y));
      float g0 = tanh_(__builtin_fmaf(wh0[2], h0, p.z));
      float o0 = sig_(__builtin_fmaf(wh0[3], h0, p.w));
      c0 = __builtin_fmaf(f0, c0, i0 * g0);
      h0 = o0 * tanh_(c0);

      float i1 = sig_(bb1[0] + __builtin_fmaf(wi1[0], h0, wh1[0] * h1));
      float f1 = sig_(bb1[1] + __builtin_fmaf(wi1[1], h0, wh1[1] * h1));
      float g1 = tanh_(bb1[2] + __builtin_fmaf(wi1[2], h0, wh1[2] * h1));
      float o1 = sig_(bb1[3] + __builtin_fmaf(wi1[3], h0, wh1[3] * h1));
      c1 = __builtin_fmaf(f1, c1, i1 * g1);
      h1 = o1 * tanh_(c1);

      float i2 = sig_(bb2[0] + __builtin_fmaf(wi2[0], h1, wh2[0] * h2));
      float f2 = sig_(bb2[1] + __builtin_fmaf(wi2[1], h1, wh2[1] * h2));
      float g2 = tanh_(bb2[2] + __builtin_fmaf(wi2[2], h1, wh2[2] * h2));
      float o2 = sig_(bb2[3] + __builtin_fmaf(wi2[3], h1, wh2[3] * h2));
      c2 = __builtin_fmaf(f2, c2, i2 * g2);
      h2 = o2 * tanh_(c2);
      ob[u] = h2;
    }
    float4 s0 = {ob[0], ob[1], ob[2], ob[3]};
    float4 s1 = {ob[4], ob[5], ob[6], ob[7]};
    float4* op = reinterpret_cast<float4*>(out + (size_t)b * TT + tb);
    op[0] = s0;
    op[1] = s1;
#pragma unroll
    for (int u = 0; u < 8; ++u) cur[u] = nxt[u];
    if (tb + 16 < TT) {
#pragma unroll
      for (int u = 0; u < 8; ++u) nxt[u] = pp[(tb + 16 + u) * BB + b];
    }
  }
}

extern "C" void kernel_launch(void* const* d_in, const int* in_sizes, int n_in,
                              void* d_out, int out_size, void* d_ws, size_t ws_size,
                              hipStream_t stream) {
  using PreT = _Float16;  // inter-layer pre buffer: fp16 (err ~5e-4 << thresh)
  const float* x      = (const float*)d_in[0];
  const float* wih_a0 = (const float*)d_in[1];
  const float* whh_a0 = (const float*)d_in[2];
  const float* bih_a0 = (const float*)d_in[3];
  const float* bhh_a0 = (const float*)d_in[4];
  const float* wih_a1 = (const float*)d_in[5];
  const float* whh_a1 = (const float*)d_in[6];
  const float* bih_a1 = (const float*)d_in[7];
  const float* bhh_a1 = (const float*)d_in[8];
  const float* wih_a2 = (const float*)d_in[9];
  const float* whh_a2 = (const float*)d_in[10];
  const float* bih_a2 = (const float*)d_in[11];
  const float* bhh_a2 = (const float*)d_in[12];
  const float* wih_b0 = (const float*)d_in[13];
  const float* whh_b0 = (const float*)d_in[14];
  const float* bih_b0 = (const float*)d_in[15];
  const float* bhh_b0 = (const float*)d_in[16];
  const float* wih_b1 = (const float*)d_in[17];
  const float* whh_b1 = (const float*)d_in[18];
  const float* bih_b1 = (const float*)d_in[19];
  const float* bhh_b1 = (const float*)d_in[20];
  const float* wih_b2 = (const float*)d_in[21];
  const float* whh_b2 = (const float*)d_in[22];
  const float* bih_b2 = (const float*)d_in[23];
  const float* bhh_b2 = (const float*)d_in[24];

  const size_t M = (size_t)BB * TT;
  PreT* P   = (PreT*)d_ws;                                     // [M,256] fp16
  float* hA = (float*)((char*)d_ws + M * 256 * sizeof(PreT));  // [M,64]
  float* pb0 = hA + M * 64;                                    // [T,B,4]
  float* out = (float*)d_out;

  rec_k<0, PreT><<<BB, 256, 0, stream>>>(x, nullptr, wih_a0, whh_a0, bih_a0, bhh_a0, hA);
  proj_k<PreT><<<(int)(M / 64) * 2, 256, 0, stream>>>(hA, wih_a1, P);
  rec_k<1, PreT><<<BB, 256, 0, stream>>>(nullptr, P, nullptr, whh_a1, bih_a1, bhh_a1, hA);
  proj_k<PreT><<<(int)(M / 64) * 2, 256, 0, stream>>>(hA, wih_a2, P);
  rec_k<1, PreT><<<BB, 256, 0, stream>>>(nullptr, P, nullptr, whh_a2, bih_a2, bhh_a2, hA);
  preb0_k<<<(int)(M / 64), 256, 0, stream>>>(hA, wih_b0, bih_b0, bhh_b0, pb0);
  b_rec_k<<<4, 64, 0, stream>>>(pb0, whh_b0, wih_b1, whh_b1, bih_b1, bhh_b1,
                                wih_b2, whh_b2, bih_b2, bhh_b2, out);
}

// Round 9
// 843.894 us; speedup vs baseline: 1.2133x; 1.0894x over previous
//
#include <hip/hip_runtime.h>

// AttackLSTM R9. B=256, T=512. a0:(1->64) a1,a2:(64->64) b0:(64->1) b1,b2:(1->1)
// R8 post-mortem: with VGPRs truly held (132), rec_k still ~213us -> the
// v_fmac_f32_dpp ops themselves are ~5-6cy (DPP-routed VALU is ~3x plain
// rate on wave64). R9 removes per-element DPP from the dot:
//   lane (q,hid) computes 4 partial dots of its OWN 16-chunk of h against
//   all 4 gate rows of hid (32 v_pk_fma_f32, full rate, no DPP), then a
//   3-DPP quad rotate-reduce combines partials: pre(row q) = sum over lanes.
// DPP per step: 64 -> 7 (3 rotate + 4 act gather). fp16 pre buffer kept.

#define BB 256
#define TT 512
#define WIN 128

typedef float v2f __attribute__((ext_vector_type(2)));

__device__ __forceinline__ float sig_(float x) {
  return __builtin_amdgcn_rcpf(1.f + __builtin_amdgcn_exp2f(-1.44269504f * x));
}
__device__ __forceinline__ float tanh_(float x) {
  return __builtin_fmaf(2.f, __builtin_amdgcn_rcpf(1.f + __builtin_amdgcn_exp2f(-2.88539008f * x)), -1.f);
}

// DPP quad_perm broadcast of quad-lane K to all 4 lanes of each quad.
template <int K>
__device__ __forceinline__ float qb_(float v) {
  return __int_as_float(__builtin_amdgcn_update_dpp(
      0, __float_as_int(v), (K | (K << 2) | (K << 4) | (K << 6)), 0xF, 0xF, true));
}
// quad rotate: lane i reads lane (i-D)&3. perm[i]=(i-D)&3.
template <int CTRL>
__device__ __forceinline__ float qrot_(float v) {
  return __int_as_float(__builtin_amdgcn_update_dpp(
      0, __float_as_int(v), CTRL, 0xF, 0xF, true));
}

// Barrier that only waits on LDS ops: global loads/stores stay in flight.
__device__ __forceinline__ void ldsbar_() {
  asm volatile("s_waitcnt lgkmcnt(0)\n\ts_barrier" ::: "memory");
}

// acc(pair) += w(pair) * h(pair)   -- one VOP3P packed-fp32 FMA
#define PKFMA(a, w, h) \
  asm("v_pk_fma_f32 %0, %1, %2, %0" : "+v"(a) : "v"(w), "v"(h))
#define KEEPP(a) asm volatile("" : "+v"(a))

// MODE 0: input = x [B,T,1] via w_ih0; MODE 1: input = pre [B,T,256] identity
// layout; thread g reads element (g&3)*64 + (g>>2) of its row.
template <int MODE, typename PreT>
__global__ __attribute__((amdgpu_flat_work_group_size(256, 256),
                          amdgpu_waves_per_eu(1, 1)))
void rec_k(
    const float* __restrict__ x,
    const PreT* __restrict__ pre_in,
    const float* __restrict__ w_ih0,
    const float* __restrict__ w_hh,   // [256,64]
    const float* __restrict__ b_ih,
    const float* __restrict__ b_hh,
    float* __restrict__ h_out)        // [B,T,64]
{
  const int b = blockIdx.x;
  const int g = threadIdx.x;
  const int q = g & 3;     // gate 0=i 1=f 2=g 3=o (also chunk index)
  const int hid = g >> 2;  // hidden unit
  const int row = q * 64 + hid;
  const int ofs = q * 64 + hid;

  __shared__ float hist[(WIN + 1) * 64];  // hist[u][hid]
  __shared__ float xs[TT];                // MODE0 input row

  // Weights: for d=0..3, gate row ((q+d)&3)*64+hid, columns [16q,16q+16)
  // as 8 v2f pairs each (for pk_fma against own h chunk).
  v2f w0[8], w1[8], w2[8], w3[8];
  {
    const v2f* p0 = reinterpret_cast<const v2f*>(w_hh + (((q + 0) & 3) * 64 + hid) * 64 + 16 * q);
    const v2f* p1 = reinterpret_cast<const v2f*>(w_hh + (((q + 1) & 3) * 64 + hid) * 64 + 16 * q);
    const v2f* p2 = reinterpret_cast<const v2f*>(w_hh + (((q + 2) & 3) * 64 + hid) * 64 + 16 * q);
    const v2f* p3 = reinterpret_cast<const v2f*>(w_hh + (((q + 3) & 3) * 64 + hid) * 64 + 16 * q);
#pragma unroll
    for (int i = 0; i < 8; ++i) { w0[i] = p0[i]; w1[i] = p1[i]; w2[i] = p2[i]; w3[i] = p3[i]; }
  }
#pragma unroll
  for (int i = 0; i < 8; ++i) { KEEPP(w0[i]); KEEPP(w1[i]); KEEPP(w2[i]); KEEPP(w3[i]); }

  const float bias = b_ih[row] + b_hh[row];
  float wi0 = 0.f;
  if constexpr (MODE == 0) wi0 = w_ih0[row];

  if constexpr (MODE == 0) {
    xs[g] = x[(size_t)b * TT + g];
    xs[g + 256] = x[(size_t)b * TT + 256 + g];
  }
  if (g < 64) hist[g] = 0.f;

  float cur[8], nxt[8];
  if constexpr (MODE == 1) {
#pragma unroll
    for (int u = 0; u < 8; ++u) cur[u] = (float)pre_in[((size_t)b * TT + u) * 256 + ofs];
#pragma unroll
    for (int u = 0; u < 8; ++u) nxt[u] = (float)pre_in[((size_t)b * TT + 8 + u) * 256 + ofs];
  }
  __syncthreads();

  float c = 0.f;

  for (int tb = 0; tb < TT; tb += 8) {
    const int lb = tb & (WIN - 1);
#pragma unroll
    for (int u = 0; u < 8; ++u) {
      const int lu = lb + u;
      // own h chunk: hist[lu][16q..16q+15] as 8 pairs (4x ds_read_b128)
      v2f hx[8];
      {
        const float4* hp = reinterpret_cast<const float4*>(hist + lu * 64 + 16 * q);
        float4 h0 = hp[0], h1 = hp[1], h2 = hp[2], h3 = hp[3];
        hx[0] = v2f{h0.x, h0.y}; hx[1] = v2f{h0.z, h0.w};
        hx[2] = v2f{h1.x, h1.y}; hx[3] = v2f{h1.z, h1.w};
        hx[4] = v2f{h2.x, h2.y}; hx[5] = v2f{h2.z, h2.w};
        hx[6] = v2f{h3.x, h3.y}; hx[7] = v2f{h3.z, h3.w};
      }
      v2f a0 = {0.f, 0.f}, a1 = {0.f, 0.f}, a2 = {0.f, 0.f}, a3 = {0.f, 0.f};
#pragma unroll
      for (int i = 0; i < 8; ++i) {
        PKFMA(a0, w0[i], hx[i]);
        PKFMA(a1, w1[i], hx[i]);
        PKFMA(a2, w2[i], hx[i]);
        PKFMA(a3, w3[i], hx[i]);
      }
      float r0 = a0.x + a0.y;  // partial for gate row q       (own)
      float r1 = a1.x + a1.y;  // partial for gate row (q+1)&3
      float r2 = a2.x + a2.y;  // partial for gate row (q+2)&3
      float r3 = a3.x + a3.y;  // partial for gate row (q+3)&3

      float base;
      if constexpr (MODE == 0) base = __builtin_fmaf(wi0, xs[tb + u], bias);
      else base = bias + cur[u];

      // quad rotate-reduce: pre(row q) = sum_l partial(l, q)
      float pre = base + r0;
      pre += qrot_<0x93>(r1);  // lane i <- lane (i-1)&3
      pre += qrot_<0x4E>(r2);  // lane i <- lane (i-2)&3
      pre += qrot_<0x39>(r3);  // lane i <- lane (i-3)&3

      float sc = (q == 2) ? -2.88539008f : -1.44269504f;
      float e = __builtin_amdgcn_exp2f(sc * pre);
      float r = __builtin_amdgcn_rcpf(1.f + e);
      float act = (q == 2) ? __builtin_fmaf(2.f, r, -1.f) : r;

      float gi = qb_<0>(act);
      float gf = qb_<1>(act);
      float gg = qb_<2>(act);
      float go = qb_<3>(act);

      c = __builtin_fmaf(gf, c, gi * gg);
      float h = go * tanh_(c);
      if (q == 0) hist[(lu + 1) * 64 + hid] = h;
      ldsbar_();
    }

    if constexpr (MODE == 1) {
#pragma unroll
      for (int u = 0; u < 8; ++u) cur[u] = nxt[u];
      if (tb + 16 < TT) {
#pragma unroll
        for (int u = 0; u < 8; ++u)
          nxt[u] = (float)pre_in[((size_t)b * TT + tb + 16 + u) * 256 + ofs];
      }
    }

    if (((tb + 8) & (WIN - 1)) == 0) {
      const int t0 = tb + 8 - WIN;
      float4* dst = reinterpret_cast<float4*>(h_out + ((size_t)b * TT + t0) * 64);
      const float4* src = reinterpret_cast<const float4*>(hist + 64);
#pragma unroll
      for (int i = 0; i < 8; ++i) dst[g + 256 * i] = src[g + 256 * i];
      if (g < 64) hist[g] = hist[WIN * 64 + g];
      ldsbar_();
    }
  }
}

// pre[rowm, c] = w[c,:]·h[rowm,:] (identity layout, coalesced stores).
template <typename PreT>
__global__ __launch_bounds__(256) void proj_k(
    const float* __restrict__ h,   // [M,64]
    const float* __restrict__ w,   // [256,64]
    PreT* __restrict__ pre)        // [M,256]
{
  __shared__ float hs[64 * 65];    // hs[k][r]
  __shared__ float ws[64 * 132];   // ws[k][c]
  const int tid = threadIdx.x;
  const int bm = blockIdx.x >> 1, half = blockIdx.x & 1;
  const size_t row0 = (size_t)bm * 64;
  const int c0 = half * 128;

#pragma unroll
  for (int i = 0; i < 16; ++i) {
    int idx = tid + 256 * i;
    int r = idx >> 6, k = idx & 63;
    hs[k * 65 + r] = h[(row0 + r) * 64 + k];
  }
#pragma unroll
  for (int i = 0; i < 32; ++i) {
    int idx = tid + 256 * i;
    int cc = idx >> 6, k = idx & 63;
    ws[k * 132 + cc] = w[(size_t)(c0 + cc) * 64 + k];
  }
  __syncthreads();

  const int rg = tid >> 4;
  const int cg = tid & 15;
  float acc[4][8];
#pragma unroll
  for (int r = 0; r < 4; ++r)
#pragma unroll
    for (int cc = 0; cc < 8; ++cc) acc[r][cc] = 0.f;

#pragma unroll 4
  for (int k = 0; k < 64; ++k) {
    float4 hv = *reinterpret_cast<const float4*>(&hs[k * 65 + 4 * rg]);
    float4 wa = *reinterpret_cast<const float4*>(&ws[k * 132 + 8 * cg]);
    float4 wb = *reinterpret_cast<const float4*>(&ws[k * 132 + 8 * cg + 4]);
    float hr[4] = {hv.x, hv.y, hv.z, hv.w};
    float wc[8] = {wa.x, wa.y, wa.z, wa.w, wb.x, wb.y, wb.z, wb.w};
#pragma unroll
    for (int r = 0; r < 4; ++r)
#pragma unroll
      for (int cc = 0; cc < 8; ++cc)
        acc[r][cc] = __builtin_fmaf(hr[r], wc[cc], acc[r][cc]);
  }

#pragma unroll
  for (int r = 0; r < 4; ++r) {
    size_t rowm = row0 + 4 * rg + r;
    PreT* dst = pre + rowm * 256 + c0 + 8 * cg;
#pragma unroll
    for (int cc = 0; cc < 8; ++cc) dst[cc] = (PreT)acc[r][cc];
  }
}

// pre_b0[t,b,q] = b_ih[q]+b_hh[q] + w[q,:]·h[b,t,:]
__global__ __launch_bounds__(256) void preb0_k(
    const float* __restrict__ h, const float* __restrict__ w,
    const float* __restrict__ bi, const float* __restrict__ bh,
    float* __restrict__ pre) {
  __shared__ float hs[64 * 68];
  const int tid = threadIdx.x;
  const int r = tid >> 2, q = tid & 3;

  float wr[64];
  {
    const float4* p = reinterpret_cast<const float4*>(w + q * 64);
#pragma unroll
    for (int i = 0; i < 16; ++i) {
      float4 v = p[i];
      wr[4 * i] = v.x; wr[4 * i + 1] = v.y; wr[4 * i + 2] = v.z; wr[4 * i + 3] = v.w;
    }
  }
  const float bias = bi[q] + bh[q];

  const size_t base = (size_t)blockIdx.x * 64;
  {
    const float4* src = reinterpret_cast<const float4*>(h + base * 64);
#pragma unroll
    for (int i = 0; i < 4; ++i) {
      int f = tid + 256 * i;
      int rr = f >> 4, kk = f & 15;
      *reinterpret_cast<float4*>(hs + rr * 68 + kk * 4) = src[f];
    }
  }
  __syncthreads();

  const float4* hr = reinterpret_cast<const float4*>(hs + r * 68);
  float a0 = bias, a1 = 0.f, a2 = 0.f, a3 = 0.f;
#pragma unroll
  for (int i = 0; i < 16; ++i) {
    float4 hv = hr[i];
    a0 = __builtin_fmaf(wr[4 * i], hv.x, a0);
    a1 = __builtin_fmaf(wr[4 * i + 1], hv.y, a1);
    a2 = __builtin_fmaf(wr[4 * i + 2], hv.z, a2);
    a3 = __builtin_fmaf(wr[4 * i + 3], hv.w, a3);
  }
  const size_t rowg = base + r;
  const int b = (int)(rowg / TT), t = (int)(rowg % TT);
  pre[((size_t)t * BB + b) * 4 + q] = (a0 + a1) + (a2 + a3);
}

// Fused b0->b1->b2, chunk-8 register pipeline (static indices).
__global__ __launch_bounds__(64, 1) void b_rec_k(
    const float* __restrict__ pre,  // [T,B,4]
    const float* __restrict__ w_hh_b0,
    const float* __restrict__ w_ih_b1, const float* __restrict__ w_hh_b1,
    const float* __restrict__ b_ih_b1, const float* __restrict__ b_hh_b1,
    const float* __restrict__ w_ih_b2, const float* __restrict__ w_hh_b2,
    const float* __restrict__ b_ih_b2, const float* __restrict__ b_hh_b2,
    float* __restrict__ out) {
  const int b = blockIdx.x * 64 + threadIdx.x;
  float wh0[4], wi1[4], wh1[4], bb1[4], wi2[4], wh2[4], bb2[4];
#pragma unroll
  for (int k = 0; k < 4; ++k) {
    wh0[k] = w_hh_b0[k];
    wi1[k] = w_ih_b1[k]; wh1[k] = w_hh_b1[k]; bb1[k] = b_ih_b1[k] + b_hh_b1[k];
    wi2[k] = w_ih_b2[k]; wh2[k] = w_hh_b2[k]; bb2[k] = b_ih_b2[k] + b_hh_b2[k];
  }
  float h0 = 0.f, c0 = 0.f, h1 = 0.f, c1 = 0.f, h2 = 0.f, c2 = 0.f;

  const float4* pp = reinterpret_cast<const float4*>(pre);
  float4 cur[8], nxt[8];
#pragma unroll
  for (int u = 0; u < 8; ++u) cur[u] = pp[u * BB + b];
#pragma unroll
  for (int u = 0; u < 8; ++u) nxt[u] = pp[(8 + u) * BB + b];

  for (int tb = 0; tb < TT; tb += 8) {
    float ob[8];
#pragma unroll
    for (int u = 0; u < 8; ++u) {
      float4 p = cur[u];
      float i0 = sig_(__builtin_fmaf(wh0[0], h0, p.x));
      float f0 = sig_(__builtin_fmaf(wh0[1], h0, p.y));
      float g0 = tanh_(__builtin_fmaf(wh0[2], h0, p.z));
      float o0 = sig_(__builtin_fmaf(wh0[3], h0, p.w));
      c0 = __builtin_fmaf(f0, c0, i0 * g0);
      h0 = o0 * tanh_(c0);

      float i1 = sig_(bb1[0] + __builtin_fmaf(wi1[0], h0, wh1[0] * h1));
      float f1 = sig_(bb1[1] + __builtin_fmaf(wi1[1], h0, wh1[1] * h1));
      float g1 = tanh_(bb1[2] + __builtin_fmaf(wi1[2], h0, wh1[2] * h1));
      float o1 = sig_(bb1[3] + __builtin_fmaf(wi1[3], h0, wh1[3] * h1));
      c1 = __builtin_fmaf(f1, c1, i1 * g1);
      h1 = o1 * tanh_(c1);

      float i2 = sig_(bb2[0] + __builtin_fmaf(wi2[0], h1, wh2[0] * h2));
      float f2 = sig_(bb2[1] + __builtin_fmaf(wi2[1], h1, wh2[1] * h2));
      float g2 = tanh_(bb2[2] + __builtin_fmaf(wi2[2], h1, wh2[2] * h2));
      float o2 = sig_(bb2[3] + __builtin_fmaf(wi2[3], h1, wh2[3] * h2));
      c2 = __builtin_fmaf(f2, c2, i2 * g2);
      h2 = o2 * tanh_(c2);
      ob[u] = h2;
    }
    float4 s0 = {ob[0], ob[1], ob[2], ob[3]};
    float4 s1 = {ob[4], ob[5], ob[6], ob[7]};
    float4* op = reinterpret_cast<float4*>(out + (size_t)b * TT + tb);
    op[0] = s0;
    op[1] = s1;
#pragma unroll
    for (int u = 0; u < 8; ++u) cur[u] = nxt[u];
    if (tb + 16 < TT) {
#pragma unroll
      for (int u = 0; u < 8; ++u) nxt[u] = pp[(tb + 16 + u) * BB + b];
    }
  }
}

extern "C" void kernel_launch(void* const* d_in, const int* in_sizes, int n_in,
                              void* d_out, int out_size, void* d_ws, size_t ws_size,
                              hipStream_t stream) {
  using PreT = _Float16;  // inter-layer pre buffer: fp16 (err ~5e-4 << thresh)
  const float* x      = (const float*)d_in[0];
  const float* wih_a0 = (const float*)d_in[1];
  const float* whh_a0 = (const float*)d_in[2];
  const float* bih_a0 = (const float*)d_in[3];
  const float* bhh_a0 = (const float*)d_in[4];
  const float* wih_a1 = (const float*)d_in[5];
  const float* whh_a1 = (const float*)d_in[6];
  const float* bih_a1 = (const float*)d_in[7];
  const float* bhh_a1 = (const float*)d_in[8];
  const float* wih_a2 = (const float*)d_in[9];
  const float* whh_a2 = (const float*)d_in[10];
  const float* bih_a2 = (const float*)d_in[11];
  const float* bhh_a2 = (const float*)d_in[12];
  const float* wih_b0 = (const float*)d_in[13];
  const float* whh_b0 = (const float*)d_in[14];
  const float* bih_b0 = (const float*)d_in[15];
  const float* bhh_b0 = (const float*)d_in[16];
  const float* wih_b1 = (const float*)d_in[17];
  const float* whh_b1 = (const float*)d_in[18];
  const float* bih_b1 = (const float*)d_in[19];
  const float* bhh_b1 = (const float*)d_in[20];
  const float* wih_b2 = (const float*)d_in[21];
  const float* whh_b2 = (const float*)d_in[22];
  const float* bih_b2 = (const float*)d_in[23];
  const float* bhh_b2 = (const float*)d_in[24];

  const size_t M = (size_t)BB * TT;
  PreT* P   = (PreT*)d_ws;                                     // [M,256] fp16
  float* hA = (float*)((char*)d_ws + M * 256 * sizeof(PreT));  // [M,64]
  float* pb0 = hA + M * 64;                                    // [T,B,4]
  float* out = (float*)d_out;

  rec_k<0, PreT><<<BB, 256, 0, stream>>>(x, nullptr, wih_a0, whh_a0, bih_a0, bhh_a0, hA);
  proj_k<PreT><<<(int)(M / 64) * 2, 256, 0, stream>>>(hA, wih_a1, P);
  rec_k<1, PreT><<<BB, 256, 0, stream>>>(nullptr, P, nullptr, whh_a1, bih_a1, bhh_a1, hA);
  proj_k<PreT><<<(int)(M / 64) * 2, 256, 0, stream>>>(hA, wih_a2, P);
  rec_k<1, PreT><<<BB, 256, 0, stream>>>(nullptr, P, nullptr, whh_a2, bih_a2, bhh_a2, hA);
  preb0_k<<<(int)(M / 64), 256, 0, stream>>>(hA, wih_b0, bih_b0, bhh_b0, pb0);
  b_rec_k<<<4, 64, 0, stream>>>(pb0, whh_b0, wih_b1, whh_b1, bih_b1, bhh_b1,
                                wih_b2, whh_b2, bih_b2, bhh_b2, out);
}

// Round 10
// 776.157 us; speedup vs baseline: 1.3192x; 1.0873x over previous
//
#include <hip/hip_runtime.h>

// AttackLSTM R10. B=256, T=512. a0:(1->64) a1,a2:(64->64) b0:(64->1) b1,b2:(1->1)
// R9 post-mortem: rec_k 174us/layer, step 818cy = ~280 busy (pk_fma is
// half-rate ~4cy) + ~540 stall (LDS pipe ~200cy: 4 waves x 4 ds_read_b128
// serialized behind each barrier; + barrier/latency chain). R10: fp16 dot.
//  - h stored fp16 in LDS; w_hh rows as half2 in VGPRs; v_dot2_f32_f16
//    (full-rate, fp32 acc): 32 insts @2cy, no partial adds.
//  - h-chunk read: 2 ds_read_b128 (was 4). Inter-layer hA buffer fp16 too.
// Quad assignment, rotate-reduce, act, ldsbar unchanged from R9 (verified).

#define BB 256
#define TT 512
#define WIN 128

typedef _Float16 v2h __attribute__((ext_vector_type(2)));
typedef _Float16 v8h __attribute__((ext_vector_type(8)));

__device__ __forceinline__ float sig_(float x) {
  return __builtin_amdgcn_rcpf(1.f + __builtin_amdgcn_exp2f(-1.44269504f * x));
}
__device__ __forceinline__ float tanh_(float x) {
  return __builtin_fmaf(2.f, __builtin_amdgcn_rcpf(1.f + __builtin_amdgcn_exp2f(-2.88539008f * x)), -1.f);
}

// DPP quad_perm broadcast of quad-lane K to all 4 lanes of each quad.
template <int K>
__device__ __forceinline__ float qb_(float v) {
  return __int_as_float(__builtin_amdgcn_update_dpp(
      0, __float_as_int(v), (K | (K << 2) | (K << 4) | (K << 6)), 0xF, 0xF, true));
}
// quad rotate: lane i reads lane (i-D)&3.
template <int CTRL>
__device__ __forceinline__ float qrot_(float v) {
  return __int_as_float(__builtin_amdgcn_update_dpp(
      0, __float_as_int(v), CTRL, 0xF, 0xF, true));
}

// Barrier that only waits on LDS ops: global loads/stores stay in flight.
__device__ __forceinline__ void ldsbar_() {
  asm volatile("s_waitcnt lgkmcnt(0)\n\ts_barrier" ::: "memory");
}

#if __has_builtin(__builtin_amdgcn_fdot2)
#define FDOT2(acc, a, b) (acc) = __builtin_amdgcn_fdot2((a), (b), (acc), false)
#else
#define FDOT2(acc, a, b) \
  (acc) = __builtin_fmaf((float)(a)[0], (float)(b)[0], \
          __builtin_fmaf((float)(a)[1], (float)(b)[1], (acc)))
#endif
#define KEEPP(a) asm volatile("" : "+v"(a))

// MODE 0: input = x [B,T,1] via w_ih0; MODE 1: input = pre [B,T,256] identity
// layout fp16; thread g reads element (g&3)*64 + (g>>2) of its row.
template <int MODE, typename PreT>
__global__ __attribute__((amdgpu_flat_work_group_size(256, 256),
                          amdgpu_waves_per_eu(1, 1)))
void rec_k(
    const float* __restrict__ x,
    const PreT* __restrict__ pre_in,
    const float* __restrict__ w_ih0,
    const float* __restrict__ w_hh,   // [256,64] fp32
    const float* __restrict__ b_ih,
    const float* __restrict__ b_hh,
    _Float16* __restrict__ h_out)     // [B,T,64] fp16
{
  const int b = blockIdx.x;
  const int g = threadIdx.x;
  const int q = g & 3;     // gate 0=i 1=f 2=g 3=o (also chunk index)
  const int hid = g >> 2;  // hidden unit
  const int row = q * 64 + hid;
  const int ofs = q * 64 + hid;

  __shared__ _Float16 hist[(WIN + 1) * 64];  // hist[u][hid], fp16
  __shared__ float xs[TT];                   // MODE0 input row

  // Weights: for d=0..3, gate row ((q+d)&3)*64+hid, columns [16q,16q+16)
  // as 8 half2 each (fp32 -> fp16 convert at start).
  v2h w0[8], w1[8], w2[8], w3[8];
  {
    const float* p0 = w_hh + (((q + 0) & 3) * 64 + hid) * 64 + 16 * q;
    const float* p1 = w_hh + (((q + 1) & 3) * 64 + hid) * 64 + 16 * q;
    const float* p2 = w_hh + (((q + 2) & 3) * 64 + hid) * 64 + 16 * q;
    const float* p3 = w_hh + (((q + 3) & 3) * 64 + hid) * 64 + 16 * q;
#pragma unroll
    for (int i = 0; i < 8; ++i) {
      w0[i] = v2h{(_Float16)p0[2 * i], (_Float16)p0[2 * i + 1]};
      w1[i] = v2h{(_Float16)p1[2 * i], (_Float16)p1[2 * i + 1]};
      w2[i] = v2h{(_Float16)p2[2 * i], (_Float16)p2[2 * i + 1]};
      w3[i] = v2h{(_Float16)p3[2 * i], (_Float16)p3[2 * i + 1]};
    }
  }
#pragma unroll
  for (int i = 0; i < 8; ++i) { KEEPP(w0[i]); KEEPP(w1[i]); KEEPP(w2[i]); KEEPP(w3[i]); }

  const float bias = b_ih[row] + b_hh[row];
  float wi0 = 0.f;
  if constexpr (MODE == 0) wi0 = w_ih0[row];

  if constexpr (MODE == 0) {
    xs[g] = x[(size_t)b * TT + g];
    xs[g + 256] = x[(size_t)b * TT + 256 + g];
  }
  if (g < 64) hist[g] = (_Float16)0.f;

  float cur[8], nxt[8];
  if constexpr (MODE == 1) {
#pragma unroll
    for (int u = 0; u < 8; ++u) cur[u] = (float)pre_in[((size_t)b * TT + u) * 256 + ofs];
#pragma unroll
    for (int u = 0; u < 8; ++u) nxt[u] = (float)pre_in[((size_t)b * TT + 8 + u) * 256 + ofs];
  }
  __syncthreads();

  float c = 0.f;

  for (int tb = 0; tb < TT; tb += 8) {
    const int lb = tb & (WIN - 1);
#pragma unroll
    for (int u = 0; u < 8; ++u) {
      const int lu = lb + u;
      // own h chunk: hist[lu][16q..16q+15] fp16 = 2x ds_read_b128
      v8h ha, hb;
      {
        const v8h* hp = reinterpret_cast<const v8h*>(hist + lu * 64 + 16 * q);
        ha = hp[0];
        hb = hp[1];
      }
      float a0 = 0.f, a1 = 0.f, a2 = 0.f, a3 = 0.f;
#pragma unroll
      for (int i = 0; i < 4; ++i) {
        v2h hp2 = v2h{ha[2 * i], ha[2 * i + 1]};
        FDOT2(a0, w0[i], hp2);
        FDOT2(a1, w1[i], hp2);
        FDOT2(a2, w2[i], hp2);
        FDOT2(a3, w3[i], hp2);
      }
#pragma unroll
      for (int i = 0; i < 4; ++i) {
        v2h hp2 = v2h{hb[2 * i], hb[2 * i + 1]};
        FDOT2(a0, w0[4 + i], hp2);
        FDOT2(a1, w1[4 + i], hp2);
        FDOT2(a2, w2[4 + i], hp2);
        FDOT2(a3, w3[4 + i], hp2);
      }

      float base;
      if constexpr (MODE == 0) base = __builtin_fmaf(wi0, xs[tb + u], bias);
      else base = bias + cur[u];

      // quad rotate-reduce: pre(row q) = sum_l partial(l, q)
      float pre = base + a0;
      pre += qrot_<0x93>(a1);  // lane i <- lane (i-1)&3
      pre += qrot_<0x4E>(a2);  // lane i <- lane (i-2)&3
      pre += qrot_<0x39>(a3);  // lane i <- lane (i-3)&3

      float sc = (q == 2) ? -2.88539008f : -1.44269504f;
      float e = __builtin_amdgcn_exp2f(sc * pre);
      float r = __builtin_amdgcn_rcpf(1.f + e);
      float act = (q == 2) ? __builtin_fmaf(2.f, r, -1.f) : r;

      float gi = qb_<0>(act);
      float gf = qb_<1>(act);
      float gg = qb_<2>(act);
      float go = qb_<3>(act);

      c = __builtin_fmaf(gf, c, gi * gg);
      float h = go * tanh_(c);
      if (q == 0) hist[(lu + 1) * 64 + hid] = (_Float16)h;
      ldsbar_();
    }

    if constexpr (MODE == 1) {
#pragma unroll
      for (int u = 0; u < 8; ++u) cur[u] = nxt[u];
      if (tb + 16 < TT) {
#pragma unroll
        for (int u = 0; u < 8; ++u)
          nxt[u] = (float)pre_in[((size_t)b * TT + tb + 16 + u) * 256 + ofs];
      }
    }

    if (((tb + 8) & (WIN - 1)) == 0) {
      // flush hist[1..WIN] (fp16) -> h_out rows (tb+8-WIN .. tb+7)
      const int t0 = tb + 8 - WIN;
      int4* dst = reinterpret_cast<int4*>(h_out + ((size_t)b * TT + t0) * 64);
      const int4* src = reinterpret_cast<const int4*>(hist + 64);
#pragma unroll
      for (int i = 0; i < 4; ++i) dst[g + 256 * i] = src[g + 256 * i];
      if (g < 64) hist[g] = hist[WIN * 64 + g];
      ldsbar_();
    }
  }
}

// pre[rowm, c] = w[c,:]·h[rowm,:] (identity layout, coalesced fp16 stores).
// h is fp16 [M,64]; compute fp32.
template <typename PreT>
__global__ __launch_bounds__(256) void proj_k(
    const _Float16* __restrict__ h,  // [M,64] fp16
    const float* __restrict__ w,     // [256,64]
    PreT* __restrict__ pre)          // [M,256]
{
  __shared__ float hs[64 * 65];    // hs[k][r]
  __shared__ float ws[64 * 132];   // ws[k][c]
  const int tid = threadIdx.x;
  const int bm = blockIdx.x >> 1, half = blockIdx.x & 1;
  const size_t row0 = (size_t)bm * 64;
  const int c0 = half * 128;

#pragma unroll
  for (int i = 0; i < 2; ++i) {
    int idx = tid + 256 * i;      // 0..511 groups of 8 halfs
    int r = idx >> 3, k8 = (idx & 7) * 8;
    v8h raw = *reinterpret_cast<const v8h*>(h + (row0 + r) * 64 + k8);
#pragma unroll
    for (int j = 0; j < 8; ++j) hs[(k8 + j) * 65 + r] = (float)raw[j];
  }
#pragma unroll
  for (int i = 0; i < 32; ++i) {
    int idx = tid + 256 * i;
    int cc = idx >> 6, k = idx & 63;
    ws[k * 132 + cc] = w[(size_t)(c0 + cc) * 64 + k];
  }
  __syncthreads();

  const int rg = tid >> 4;
  const int cg = tid & 15;
  float acc[4][8];
#pragma unroll
  for (int r = 0; r < 4; ++r)
#pragma unroll
    for (int cc = 0; cc < 8; ++cc) acc[r][cc] = 0.f;

#pragma unroll 4
  for (int k = 0; k < 64; ++k) {
    float4 hv = *reinterpret_cast<const float4*>(&hs[k * 65 + 4 * rg]);
    float4 wa = *reinterpret_cast<const float4*>(&ws[k * 132 + 8 * cg]);
    float4 wb = *reinterpret_cast<const float4*>(&ws[k * 132 + 8 * cg + 4]);
    float hr[4] = {hv.x, hv.y, hv.z, hv.w};
    float wc[8] = {wa.x, wa.y, wa.z, wa.w, wb.x, wb.y, wb.z, wb.w};
#pragma unroll
    for (int r = 0; r < 4; ++r)
#pragma unroll
      for (int cc = 0; cc < 8; ++cc)
        acc[r][cc] = __builtin_fmaf(hr[r], wc[cc], acc[r][cc]);
  }

#pragma unroll
  for (int r = 0; r < 4; ++r) {
    size_t rowm = row0 + 4 * rg + r;
    PreT* dst = pre + rowm * 256 + c0 + 8 * cg;
#pragma unroll
    for (int cc = 0; cc < 8; ++cc) dst[cc] = (PreT)acc[r][cc];
  }
}

// pre_b0[t,b,q] = b_ih[q]+b_hh[q] + w[q,:]·h[b,t,:]; h fp16.
__global__ __launch_bounds__(256) void preb0_k(
    const _Float16* __restrict__ h, const float* __restrict__ w,
    const float* __restrict__ bi, const float* __restrict__ bh,
    float* __restrict__ pre) {
  __shared__ float hs[64 * 68];
  const int tid = threadIdx.x;
  const int r = tid >> 2, q = tid & 3;

  float wr[64];
  {
    const float4* p = reinterpret_cast<const float4*>(w + q * 64);
#pragma unroll
    for (int i = 0; i < 16; ++i) {
      float4 v = p[i];
      wr[4 * i] = v.x; wr[4 * i + 1] = v.y; wr[4 * i + 2] = v.z; wr[4 * i + 3] = v.w;
    }
  }
  const float bias = bi[q] + bh[q];

  const size_t base = (size_t)blockIdx.x * 64;
#pragma unroll
  for (int i = 0; i < 2; ++i) {
    int idx = tid + 256 * i;      // 0..511 groups of 8 halfs
    int rr = idx >> 3, k8 = (idx & 7) * 8;
    v8h raw = *reinterpret_cast<const v8h*>(h + (base + rr) * 64 + k8);
    float4 f0 = {(float)raw[0], (float)raw[1], (float)raw[2], (float)raw[3]};
    float4 f1 = {(float)raw[4], (float)raw[5], (float)raw[6], (float)raw[7]};
    *reinterpret_cast<float4*>(&hs[rr * 68 + k8]) = f0;
    *reinterpret_cast<float4*>(&hs[rr * 68 + k8 + 4]) = f1;
  }
  __syncthreads();

  const float4* hr = reinterpret_cast<const float4*>(hs + r * 68);
  float a0 = bias, a1 = 0.f, a2 = 0.f, a3 = 0.f;
#pragma unroll
  for (int i = 0; i < 16; ++i) {
    float4 hv = hr[i];
    a0 = __builtin_fmaf(wr[4 * i], hv.x, a0);
    a1 = __builtin_fmaf(wr[4 * i + 1], hv.y, a1);
    a2 = __builtin_fmaf(wr[4 * i + 2], hv.z, a2);
    a3 = __builtin_fmaf(wr[4 * i + 3], hv.w, a3);
  }
  const size_t rowg = base + r;
  const int b = (int)(rowg / TT), t = (int)(rowg % TT);
  pre[((size_t)t * BB + b) * 4 + q] = (a0 + a1) + (a2 + a3);
}

// Fused b0->b1->b2, chunk-8 register pipeline (static indices).
__global__ __launch_bounds__(64, 1) void b_rec_k(
    const float* __restrict__ pre,  // [T,B,4]
    const float* __restrict__ w_hh_b0,
    const float* __restrict__ w_ih_b1, const float* __restrict__ w_hh_b1,
    const float* __restrict__ b_ih_b1, const float* __restrict__ b_hh_b1,
    const float* __restrict__ w_ih_b2, const float* __restrict__ w_hh_b2,
    const float* __restrict__ b_ih_b2, const float* __restrict__ b_hh_b2,
    float* __restrict__ out) {
  const int b = blockIdx.x * 64 + threadIdx.x;
  float wh0[4], wi1[4], wh1[4], bb1[4], wi2[4], wh2[4], bb2[4];
#pragma unroll
  for (int k = 0; k < 4; ++k) {
    wh0[k] = w_hh_b0[k];
    wi1[k] = w_ih_b1[k]; wh1[k] = w_hh_b1[k]; bb1[k] = b_ih_b1[k] + b_hh_b1[k];
    wi2[k] = w_ih_b2[k]; wh2[k] = w_hh_b2[k]; bb2[k] = b_ih_b2[k] + b_hh_b2[k];
  }
  float h0 = 0.f, c0 = 0.f, h1 = 0.f, c1 = 0.f, h2 = 0.f, c2 = 0.f;

  const float4* pp = reinterpret_cast<const float4*>(pre);
  float4 cur[8], nxt[8];
#pragma unroll
  for (int u = 0; u < 8; ++u) cur[u] = pp[u * BB + b];
#pragma unroll
  for (int u = 0; u < 8; ++u) nxt[u] = pp[(8 + u) * BB + b];

  for (int tb = 0; tb < TT; tb += 8) {
    float ob[8];
#pragma unroll
    for (int u = 0; u < 8; ++u) {
      float4 p = cur[u];
      float i0 = sig_(__builtin_fmaf(wh0[0], h0, p.x));
      float f0 = sig_(__builtin_fmaf(wh0[1], h0, p.y));
      float g0 = tanh_(__builtin_fmaf(wh0[2], h0, p.z));
      float o0 = sig_(__builtin_fmaf(wh0[3], h0, p.w));
      c0 = __builtin_fmaf(f0, c0, i0 * g0);
      h0 = o0 * tanh_(c0);

      float i1 = sig_(bb1[0] + __builtin_fmaf(wi1[0], h0, wh1[0] * h1));
      float f1 = sig_(bb1[1] + __builtin_fmaf(wi1[1], h0, wh1[1] * h1));
      float g1 = tanh_(bb1[2] + __builtin_fmaf(wi1[2], h0, wh1[2] * h1));
      float o1 = sig_(bb1[3] + __builtin_fmaf(wi1[3], h0, wh1[3] * h1));
      c1 = __builtin_fmaf(f1, c1, i1 * g1);
      h1 = o1 * tanh_(c1);

      float i2 = sig_(bb2[0] + __builtin_fmaf(wi2[0], h1, wh2[0] * h2));
      float f2 = sig_(bb2[1] + __builtin_fmaf(wi2[1], h1, wh2[1] * h2));
      float g2 = tanh_(bb2[2] + __builtin_fmaf(wi2[2], h1, wh2[2] * h2));
      float o2 = sig_(bb2[3] + __builtin_fmaf(wi2[3], h1, wh2[3] * h2));
      c2 = __builtin_fmaf(f2, c2, i2 * g2);
      h2 = o2 * tanh_(c2);
      ob[u] = h2;
    }
    float4 s0 = {ob[0], ob[1], ob[2], ob[3]};
    float4 s1 = {ob[4], ob[5], ob[6], ob[7]};
    float4* op = reinterpret_cast<float4*>(out + (size_t)b * TT + tb);
    op[0] = s0;
    op[1] = s1;
#pragma unroll
    for (int u = 0; u < 8; ++u) cur[u] = nxt[u];
    if (tb + 16 < TT) {
#pragma unroll
      for (int u = 0; u < 8; ++u) nxt[u] = pp[(tb + 16 + u) * BB + b];
    }
  }
}

extern "C" void kernel_launch(void* const* d_in, const int* in_sizes, int n_in,
                              void* d_out, int out_size, void* d_ws, size_t ws_size,
                              hipStream_t stream) {
  using PreT = _Float16;  // inter-layer pre buffer fp16
  const float* x      = (const float*)d_in[0];
  const float* wih_a0 = (const float*)d_in[1];
  const float* whh_a0 = (const float*)d_in[2];
  const float* bih_a0 = (const float*)d_in[3];
  const float* bhh_a0 = (const float*)d_in[4];
  const float* wih_a1 = (const float*)d_in[5];
  const float* whh_a1 = (const float*)d_in[6];
  const float* bih_a1 = (const float*)d_in[7];
  const float* bhh_a1 = (const float*)d_in[8];
  const float* wih_a2 = (const float*)d_in[9];
  const float* whh_a2 = (const float*)d_in[10];
  const float* bih_a2 = (const float*)d_in[11];
  const float* bhh_a2 = (const float*)d_in[12];
  const float* wih_b0 = (const float*)d_in[13];
  const float* whh_b0 = (const float*)d_in[14];
  const float* bih_b0 = (const float*)d_in[15];
  const float* bhh_b0 = (const float*)d_in[16];
  const float* wih_b1 = (const float*)d_in[17];
  const float* whh_b1 = (const float*)d_in[18];
  const float* bih_b1 = (const float*)d_in[19];
  const float* bhh_b1 = (const float*)d_in[20];
  const float* wih_b2 = (const float*)d_in[21];
  const float* whh_b2 = (const float*)d_in[22];
  const float* bih_b2 = (const float*)d_in[23];
  const float* bhh_b2 = (const float*)d_in[24];

  const size_t M = (size_t)BB * TT;
  PreT* P       = (PreT*)d_ws;                                      // [M,256] fp16
  _Float16* hA  = (_Float16*)((char*)d_ws + M * 256 * sizeof(PreT));// [M,64] fp16
  float* pb0    = (float*)(hA + M * 64);                            // [T,B,4] fp32
  float* out    = (float*)d_out;

  rec_k<0, PreT><<<BB, 256, 0, stream>>>(x, nullptr, wih_a0, whh_a0, bih_a0, bhh_a0, hA);
  proj_k<PreT><<<(int)(M / 64) * 2, 256, 0, stream>>>(hA, wih_a1, P);
  rec_k<1, PreT><<<BB, 256, 0, stream>>>(nullptr, P, nullptr, whh_a1, bih_a1, bhh_a1, hA);
  proj_k<PreT><<<(int)(M / 64) * 2, 256, 0, stream>>>(hA, wih_a2, P);
  rec_k<1, PreT><<<BB, 256, 0, stream>>>(nullptr, P, nullptr, whh_a2, bih_a2, bhh_a2, hA);
  preb0_k<<<(int)(M / 64), 256, 0, stream>>>(hA, wih_b0, bih_b0, bhh_b0, pb0);
  b_rec_k<<<4, 64, 0, stream>>>(pb0, whh_b0, wih_b1, whh_b1, bih_b1, bhh_b1,
                                wih_b2, whh_b2, bih_b2, bhh_b2, out);
}